// Round 5
// baseline (221.427 us; speedup 1.0000x reference)
//
#include <hip/hip_runtime.h>
#include <math.h>

#define NPTS 2048
#define BLOCK 1024               // 16 waves
#define BPB 4                    // batches per block (4 waves per batch)
#define WPB 4                    // waves per batch
// per wave: 512 contiguous points, per lane 8 points = 2 x (3+3 float4 loads)

// Max-TLP experiment (rerun; round-4 bench died to container infra, no data).
// Rounds 0-3 (four disjoint structures, occupancy 17-38%) all hit 80.2-80.7us,
// including an LLC-warm replay with FETCH~0 -> the wall is the beyond-L2
// delivery rate at ~2.5 TB/s, far under the 6.3 TB/s copy ubench. All rounds
// exposed only ~48-96KB in flight per CU. This kernel removes every per-wave
// dependency chain (one shot of 12 independent float4 loads per wave-half)
// and buys parallelism purely with occupancy: 32 waves/CU (100%), ~192KB/CU
// in flight. If this also lands at 80us, the 2.5TB/s cap is real.
__global__ __launch_bounds__(BLOCK, 8) void kabsch_kernel(
    const float* __restrict__ P, const float* __restrict__ C,
    float* __restrict__ out, int B) {
  const int w = threadIdx.x >> 6;       // wave in block
  const int lane = threadIdx.x & 63;
  const int batch = blockIdx.x * BPB + (w >> 2);  // 4 waves per batch
  const int slice = w & 3;                        // quarter of the batch

  // 0-2 sum(p), 3-5 sum(c), 6 sum|p|^2, 7 sum|c|^2, 8-16 sum p_j*c_k
  float acc[17];
#pragma unroll
  for (int i = 0; i < 17; i++) acc[i] = 0.f;

#define ACCUM(PA, PB, PQ, CA, CB, CQ)                                   \
  do {                                                                  \
    const float Px[4] = {PA.x, PA.w, PB.z, PQ.y};                       \
    const float Py[4] = {PA.y, PB.x, PB.w, PQ.z};                       \
    const float Pz[4] = {PA.z, PB.y, PQ.x, PQ.w};                       \
    const float Cx[4] = {CA.x, CA.w, CB.z, CQ.y};                       \
    const float Cy[4] = {CA.y, CB.x, CB.w, CQ.z};                       \
    const float Cz[4] = {CA.z, CB.y, CQ.x, CQ.w};                       \
    _Pragma("unroll")                                                   \
    for (int i = 0; i < 4; i++) {                                       \
      const float px = Px[i], py = Py[i], pz = Pz[i];                   \
      const float cx = Cx[i], cy = Cy[i], cz = Cz[i];                   \
      acc[0] += px; acc[1] += py; acc[2] += pz;                         \
      acc[3] += cx; acc[4] += cy; acc[5] += cz;                         \
      acc[6] += px * px + py * py + pz * pz;                            \
      acc[7] += cx * cx + cy * cy + cz * cz;                            \
      acc[8]  += px * cx; acc[9]  += px * cy; acc[10] += px * cz;       \
      acc[11] += py * cx; acc[12] += py * cy; acc[13] += py * cz;       \
      acc[14] += pz * cx; acc[15] += pz * cy; acc[16] += pz * cz;       \
    }                                                                   \
  } while (0)

  if (batch < B) {
    // float4 base: batch*1536 + slice*384 + iter*192 + 3*lane
    const float4* p4 = (const float4*)P + (size_t)batch * 1536 + slice * 384 + 3 * lane;
    const float4* c4 = (const float4*)C + (size_t)batch * 1536 + slice * 384 + 3 * lane;
#pragma unroll
    for (int it = 0; it < 2; ++it) {
      const float4 pa = p4[it * 192],     pb = p4[it * 192 + 1], pq = p4[it * 192 + 2];
      const float4 ca = c4[it * 192],     cb = c4[it * 192 + 1], cq = c4[it * 192 + 2];
      ACCUM(pa, pb, pq, ca, cb, cq);
    }
  }

  // wave (64-lane) butterfly reduce; lane 0 ends with the wave's sums
#pragma unroll
  for (int off = 32; off > 0; off >>= 1) {
#pragma unroll
    for (int i = 0; i < 17; i++) acc[i] += __shfl_down(acc[i], off);
  }

  __shared__ float red[BPB * WPB][17];
  if (lane == 0) {
#pragma unroll
    for (int i = 0; i < 17; i++) red[w][i] = acc[i];
  }
  __syncthreads();

  // lanes 0-3 of wave 0: one double-precision epilogue per batch, in parallel
  double v = 0.0;
  if (threadIdx.x < BPB) {
    const int t = threadIdx.x;
    const int bt = blockIdx.x * BPB + t;
    if (bt < B) {
      double s[17];
#pragma unroll
      for (int i = 0; i < 17; i++) {
        float f = red[t * WPB][i];
#pragma unroll
        for (int j = 1; j < WPB; j++) f += red[t * WPB + j][i];
        s[i] = (double)f;
      }
      const double invN = 1.0 / (double)NPTS;
      const double spx = s[0], spy = s[1], spz = s[2];
      const double scx = s[3], scy = s[4], scz = s[5];
      const double Ep = s[6] - (spx * spx + spy * spy + spz * spz) * invN;
      const double Ec = s[7] - (scx * scx + scy * scy + scz * scz) * invN;
      const double a00 = s[8]  - spx * scx * invN, a01 = s[9]  - spx * scy * invN, a02 = s[10] - spx * scz * invN;
      const double a10 = s[11] - spy * scx * invN, a11 = s[12] - spy * scy * invN, a12 = s[13] - spy * scz * invN;
      const double a20 = s[14] - spz * scx * invN, a21 = s[15] - spz * scy * invN, a22 = s[16] - spz * scz * invN;
      const double det = a00 * (a11 * a22 - a12 * a21)
                       - a01 * (a10 * a22 - a12 * a20)
                       + a02 * (a10 * a21 - a11 * a20);
      const double b00 = a00 * a00 + a10 * a10 + a20 * a20;
      const double b11 = a01 * a01 + a11 * a11 + a21 * a21;
      const double b22 = a02 * a02 + a12 * a12 + a22 * a22;
      const double b01 = a00 * a01 + a10 * a11 + a20 * a21;
      const double b02 = a00 * a02 + a10 * a12 + a20 * a22;
      const double b12 = a01 * a02 + a11 * a12 + a21 * a22;
      const double q = (b00 + b11 + b22) / 3.0;
      const double p1 = b01 * b01 + b02 * b02 + b12 * b12;
      const double d0 = b00 - q, d1 = b11 - q, d2 = b22 - q;
      const double p2 = d0 * d0 + d1 * d1 + d2 * d2 + 2.0 * p1;
      double e1, e2, e3;
      if (p2 < 1e-30) {
        e1 = e2 = e3 = q;
      } else {
        const double pp = sqrt(p2 / 6.0);
        const double inv = 1.0 / pp;
        const double c00 = d0 * inv, c11 = d1 * inv, c22 = d2 * inv;
        const double c01 = b01 * inv, c02 = b02 * inv, c12 = b12 * inv;
        double r = 0.5 * (c00 * (c11 * c22 - c12 * c12)
                        - c01 * (c01 * c22 - c12 * c02)
                        + c02 * (c01 * c12 - c11 * c02));
        r = fmin(1.0, fmax(-1.0, r));
        const double phi = acos(r) / 3.0;
        e1 = q + 2.0 * pp * cos(phi);
        e3 = q + 2.0 * pp * cos(phi + 2.0943951023931953);  // smallest
        e2 = 3.0 * q - e1 - e3;
      }
      const double s1 = sqrt(fmax(e1, 0.0));
      const double s2 = sqrt(fmax(e2, 0.0));
      const double s3 = sqrt(fmax(e3, 0.0));
      const double dsign = (det > 0.0) ? 1.0 : ((det < 0.0) ? -1.0 : 0.0);
      const double trRS = s1 + s2 + dsign * s3;  // tr(R A^T)
      const double msd = (Ep + Ec - 2.0 * trRS) * invN;
      v = sqrt(fmax(msd, 0.0));
    }
  }
  // sum the 4 epilogue lanes (lanes >=4 carry 0), one atomic per block
  v += __shfl_down(v, 2);
  v += __shfl_down(v, 1);
  if (threadIdx.x == 0) atomicAdd(out, (float)(v / (double)B));
}

extern "C" void kernel_launch(void* const* d_in, const int* in_sizes, int n_in,
                              void* d_out, int out_size, void* d_ws, size_t ws_size,
                              hipStream_t stream) {
  const float* P = (const float*)d_in[0];
  const float* C = (const float*)d_in[1];
  float* out = (float*)d_out;
  const int B = in_sizes[0] / (NPTS * 3);
  hipMemsetAsync(out, 0, sizeof(float), stream);  // d_out poisoned before every call
  kabsch_kernel<<<(B + BPB - 1) / BPB, BLOCK, 0, stream>>>(P, C, out, B);
}

// Round 8
// 216.891 us; speedup vs baseline: 1.0209x; 1.0209x over previous
//
#include <hip/hip_runtime.h>
#include <math.h>

#define NPTS 2048
#define BLOCK 256
#define FPB (NPTS * 3)      // floats per tensor per batch = 6144
#define SHOT_OFF 3072       // floats: thread t's 2nd triplet starts here

// Round 8: forced 12-deep load pipeline, spill-safe and hoist-safe.
// Rounds 0-5 (occupancy 17-54%, 16B vs 48B lanes, VGPR vs LDS-DMA) all hit
// 80-83us = ~2.5 TB/s because every structure degenerated to ~16KB
// outstanding/CU (compiler register-lean load scheduling each time;
// VGPR_Count 40/40/32). Round 7's overlap variant corrupted data (suspected
// spill of in-flight asm outputs at ~130 live regs, or consumer hoist past
// the wait). This version: ONE batch per block (peak live ~83 VGPR < 128
// cap, no spills; no other vmem between issue and wait so vmcnt counts are
// exact), and consume-ordering is enforced by DATAFLOW: an empty volatile
// asm re-defines each consumed float component-wise after the counted
// vmcnt wait (single-reg "+v" ties are legal; only 128-bit tuple ties
// aren't). No scheduler pass can hoist consumers above the wait.

#define ISSUE12(O0,O1,O2,O3,O4,O5,O6,O7,O8,O9,O10,O11, p0,c0,p1,c1)      \
  asm volatile(                                                          \
      "global_load_dwordx4 %0, %12, off\n\t"                             \
      "global_load_dwordx4 %1, %12, off offset:16\n\t"                   \
      "global_load_dwordx4 %2, %12, off offset:32\n\t"                   \
      "global_load_dwordx4 %3, %13, off\n\t"                             \
      "global_load_dwordx4 %4, %13, off offset:16\n\t"                   \
      "global_load_dwordx4 %5, %13, off offset:32\n\t"                   \
      "global_load_dwordx4 %6, %14, off\n\t"                             \
      "global_load_dwordx4 %7, %14, off offset:16\n\t"                   \
      "global_load_dwordx4 %8, %14, off offset:32\n\t"                   \
      "global_load_dwordx4 %9, %15, off\n\t"                             \
      "global_load_dwordx4 %10, %15, off offset:16\n\t"                  \
      "global_load_dwordx4 %11, %15, off offset:32\n\t"                  \
      : "=&v"(O0), "=&v"(O1), "=&v"(O2), "=&v"(O3), "=&v"(O4), "=&v"(O5),\
        "=&v"(O6), "=&v"(O7), "=&v"(O8), "=&v"(O9), "=&v"(O10), "=&v"(O11)\
      : "v"(p0), "v"(c0), "v"(p1), "v"(c1))

#define TIE4(V) "+v"((V).x), "+v"((V).y), "+v"((V).z), "+v"((V).w)

// counted wait, then dataflow-pin the 6 float4s about to be consumed
#define WAIT_PIN6(N, a, b, c, d, e, f)                                   \
  do {                                                                   \
    asm volatile("s_waitcnt vmcnt(" #N ")" ::: "memory");                \
    asm volatile("" : TIE4(a), TIE4(b), TIE4(c));                        \
    asm volatile("" : TIE4(d), TIE4(e), TIE4(f));                        \
    __builtin_amdgcn_sched_barrier(0);                                   \
  } while (0)

#define ACCUM(PA, PB, PQ, CA, CB, CQ)                                   \
  do {                                                                  \
    const float Px[4] = {PA.x, PA.w, PB.z, PQ.y};                       \
    const float Py[4] = {PA.y, PB.x, PB.w, PQ.z};                       \
    const float Pz[4] = {PA.z, PB.y, PQ.x, PQ.w};                       \
    const float Cx[4] = {CA.x, CA.w, CB.z, CQ.y};                       \
    const float Cy[4] = {CA.y, CB.x, CB.w, CQ.z};                       \
    const float Cz[4] = {CA.z, CB.y, CQ.x, CQ.w};                       \
    _Pragma("unroll")                                                   \
    for (int i = 0; i < 4; i++) {                                       \
      const float px = Px[i], py = Py[i], pz = Pz[i];                   \
      const float cx = Cx[i], cy = Cy[i], cz = Cz[i];                   \
      acc[0] += px; acc[1] += py; acc[2] += pz;                         \
      acc[3] += cx; acc[4] += cy; acc[5] += cz;                         \
      acc[6] += px * px + py * py + pz * pz;                            \
      acc[7] += cx * cx + cy * cy + cz * cz;                            \
      acc[8]  += px * cx; acc[9]  += px * cy; acc[10] += px * cz;       \
      acc[11] += py * cx; acc[12] += py * cy; acc[13] += py * cz;       \
      acc[14] += pz * cx; acc[15] += pz * cy; acc[16] += pz * cz;       \
    }                                                                   \
  } while (0)

__device__ __forceinline__ double kabsch_epilogue(const float* sf) {
  double s[17];
#pragma unroll
  for (int i = 0; i < 17; i++) s[i] = (double)sf[i];
  const double invN = 1.0 / (double)NPTS;
  const double spx = s[0], spy = s[1], spz = s[2];
  const double scx = s[3], scy = s[4], scz = s[5];
  const double Ep = s[6] - (spx * spx + spy * spy + spz * spz) * invN;
  const double Ec = s[7] - (scx * scx + scy * scy + scz * scz) * invN;
  const double a00 = s[8]  - spx * scx * invN, a01 = s[9]  - spx * scy * invN, a02 = s[10] - spx * scz * invN;
  const double a10 = s[11] - spy * scx * invN, a11 = s[12] - spy * scy * invN, a12 = s[13] - spy * scz * invN;
  const double a20 = s[14] - spz * scx * invN, a21 = s[15] - spz * scy * invN, a22 = s[16] - spz * scz * invN;
  const double det = a00 * (a11 * a22 - a12 * a21)
                   - a01 * (a10 * a22 - a12 * a20)
                   + a02 * (a10 * a21 - a11 * a20);
  const double b00 = a00 * a00 + a10 * a10 + a20 * a20;
  const double b11 = a01 * a01 + a11 * a11 + a21 * a21;
  const double b22 = a02 * a02 + a12 * a12 + a22 * a22;
  const double b01 = a00 * a01 + a10 * a11 + a20 * a21;
  const double b02 = a00 * a02 + a10 * a12 + a20 * a22;
  const double b12 = a01 * a02 + a11 * a12 + a21 * a22;
  const double q = (b00 + b11 + b22) / 3.0;
  const double p1 = b01 * b01 + b02 * b02 + b12 * b12;
  const double d0 = b00 - q, d1 = b11 - q, d2 = b22 - q;
  const double p2 = d0 * d0 + d1 * d1 + d2 * d2 + 2.0 * p1;
  double e1, e2, e3;
  if (p2 < 1e-30) {
    e1 = e2 = e3 = q;
  } else {
    const double pp = sqrt(p2 / 6.0);
    const double inv = 1.0 / pp;
    const double c00 = d0 * inv, c11 = d1 * inv, c22 = d2 * inv;
    const double c01 = b01 * inv, c02 = b02 * inv, c12 = b12 * inv;
    double r = 0.5 * (c00 * (c11 * c22 - c12 * c12)
                    - c01 * (c01 * c22 - c12 * c02)
                    + c02 * (c01 * c12 - c11 * c02));
    r = fmin(1.0, fmax(-1.0, r));
    const double phi = acos(r) / 3.0;
    e1 = q + 2.0 * pp * cos(phi);
    e3 = q + 2.0 * pp * cos(phi + 2.0943951023931953);  // smallest
    e2 = 3.0 * q - e1 - e3;
  }
  const double s1 = sqrt(fmax(e1, 0.0));
  const double s2 = sqrt(fmax(e2, 0.0));
  const double s3 = sqrt(fmax(e3, 0.0));
  const double dsign = (det > 0.0) ? 1.0 : ((det < 0.0) ? -1.0 : 0.0);
  const double trRS = s1 + s2 + dsign * s3;  // tr(R A^T)
  const double msd = (Ep + Ec - 2.0 * trRS) * invN;
  return sqrt(fmax(msd, 0.0));
}

__global__ __launch_bounds__(BLOCK, 4) void kabsch_kernel(
    const float* __restrict__ P, const float* __restrict__ C,
    float* __restrict__ out, int B) {
  const int t = threadIdx.x;
  const int wave = t >> 6, lane = t & 63;
  const int b = blockIdx.x;
  __shared__ float red[BLOCK / 64][17];

  // thread t owns triplets t (floats 12t..12t+11) and t+256 (offset 3072)
  const float* p0 = P + (size_t)b * FPB + 12 * t;
  const float* c0 = C + (size_t)b * FPB + 12 * t;
  const float* p1 = p0 + SHOT_OFF;
  const float* c1 = c0 + SHOT_OFF;

  float4 A0, A1, A2, A3, A4, A5, A6, A7, A8, A9, A10, A11;
  ISSUE12(A0, A1, A2, A3, A4, A5, A6, A7, A8, A9, A10, A11,
          p0, c0, p1, c1);           // 12 dwordx4 in flight per thread

  float acc[17];
#pragma unroll
  for (int i = 0; i < 17; i++) acc[i] = 0.f;

  WAIT_PIN6(6, A0, A1, A2, A3, A4, A5);   // shot 0 landed (6 still in flight)
  ACCUM(A0, A1, A2, A3, A4, A5);

  WAIT_PIN6(0, A6, A7, A8, A9, A10, A11); // shot 1 landed
  ACCUM(A6, A7, A8, A9, A10, A11);

  // wave (64-lane) butterfly reduce; lane 0 ends with the wave's sums
#pragma unroll
  for (int off = 32; off > 0; off >>= 1) {
#pragma unroll
    for (int i = 0; i < 17; i++) acc[i] += __shfl_down(acc[i], off);
  }
  if (lane == 0) {
#pragma unroll
    for (int i = 0; i < 17; i++) red[wave][i] = acc[i];
  }
  __syncthreads();

  if (t == 0) {
    float s[17];
#pragma unroll
    for (int i = 0; i < 17; i++) {
      float v = red[0][i];
#pragma unroll
      for (int w = 1; w < BLOCK / 64; w++) v += red[w][i];
      s[i] = v;
    }
    atomicAdd(out, (float)(kabsch_epilogue(s) / (double)B));
  }
}

extern "C" void kernel_launch(void* const* d_in, const int* in_sizes, int n_in,
                              void* d_out, int out_size, void* d_ws, size_t ws_size,
                              hipStream_t stream) {
  const float* P = (const float*)d_in[0];
  const float* C = (const float*)d_in[1];
  float* out = (float*)d_out;
  const int B = in_sizes[0] / FPB;
  hipMemsetAsync(out, 0, sizeof(float), stream);  // d_out poisoned before every call
  kabsch_kernel<<<B, BLOCK, 0, stream>>>(P, C, out, B);
}